// Round 3
// baseline (279.445 us; speedup 1.0000x reference)
//
#include <hip/hip_runtime.h>

typedef unsigned short ushort_t;
typedef __attribute__((ext_vector_type(8))) __bf16 bf16x8;
typedef __attribute__((ext_vector_type(4))) float floatx4;

__device__ __forceinline__ ushort_t f2bf(float f) {
    unsigned int u = __builtin_bit_cast(unsigned int, f);
    u = (u + 0x7fffu + ((u >> 16) & 1u)) >> 16;
    return (ushort_t)u;
}

__device__ __forceinline__ void async16(const ushort_t* g, ushort_t* l) {
    __builtin_amdgcn_global_load_lds(
        (const __attribute__((address_space(1))) unsigned int*)g,
        (__attribute__((address_space(3))) unsigned int*)l,
        16 /*bytes*/, 0 /*offset*/, 0 /*aux*/);
}

// XOR-swizzled LDS offset (ushort index) of the 8-elem group (row, cg).
__device__ __forceinline__ int sw(int row, int cg) {
    return ((row << 2) + ((cg ^ row ^ (row >> 2)) & 3)) << 3;
}

// ---------------------------------------------------------------------------
// Core bf16 GEMM tile: acc[m][n] += sum_k A[m][k] * B[n][k]  (both K-contig)
// 128x128 tile, 512 threads = 8 waves in 2(m) x 4(n); wave-tile 64x32:
// IM=4 x IN=2 mfma(16x16x32). acc = 32 AGPR/thread (vs 64 at 4x4) so
// ~80 total regs -> 6 waves/SIMD -> 3 blocks/CU = 24 waves/CU residency.
// ---------------------------------------------------------------------------
__device__ __forceinline__ void gemm_core512(
    const ushort_t* __restrict__ A, int lda,
    const ushort_t* __restrict__ B, int ldb,
    int K, int tile_m, int tile_n,
    ushort_t* As, ushort_t* Bs,
    floatx4 (&acc)[4][2]) {

    const int tid  = threadIdx.x;
    const int lane = tid & 63;
    const int wave = tid >> 6;
    const int wm   = wave >> 2;      // 0..1
    const int wn   = wave & 3;       // 0..3
    const int quad = lane >> 4;
    const int l16  = lane & 15;

#pragma unroll
    for (int i = 0; i < 4; i++)
#pragma unroll
        for (int j = 0; j < 2; j++) acc[i][j] = (floatx4){0.f, 0.f, 0.f, 0.f};

    // one 16B staging segment per thread per matrix (512 segs per tile)
    const int srow = tid >> 2;
    const int scg  = (tid ^ srow ^ (srow >> 2)) & 3;
    const ushort_t* ga = A + (long)(srow + tile_m) * lda + scg * 8;
    const ushort_t* gb = B + (long)(srow + tile_n) * ldb + scg * 8;
    ushort_t* la = &As[tid * 8];
    ushort_t* lb = &Bs[tid * 8];

    for (int k0 = 0; k0 < K; k0 += 32) {
        __syncthreads();
        async16(ga + k0, la);
        async16(gb + k0, lb);
        __syncthreads();

        bf16x8 af[4], bfr[2];
#pragma unroll
        for (int im = 0; im < 4; im++)
            af[im] = *(const bf16x8*)&As[sw(wm * 64 + im * 16 + l16, quad)];
#pragma unroll
        for (int in = 0; in < 2; in++)
            bfr[in] = *(const bf16x8*)&Bs[sw(wn * 32 + in * 16 + l16, quad)];
#pragma unroll
        for (int im = 0; im < 4; im++)
#pragma unroll
            for (int in = 0; in < 2; in++)
                acc[im][in] = __builtin_amdgcn_mfma_f32_16x16x32_bf16(
                    af[im], bfr[in], acc[im][in], 0, 0, 0);
    }
}

// ---------------------------------------------------------------------------
// fp32 -> bf16 conversion for x, W_q, W_k, W_v ; trailing blocks zero lsum
// ---------------------------------------------------------------------------
__global__ void cvt_kernel(const float* __restrict__ x,
                           const float* __restrict__ wq,
                           const float* __restrict__ wk,
                           const float* __restrict__ wv,
                           ushort_t* __restrict__ dst,
                           float* __restrict__ lsum) {
    if (blockIdx.x >= 11264) {
        int idx = (blockIdx.x - 11264) * 256 + threadIdx.x;  // [0,2048)
        ((float4*)lsum)[idx] = (float4){0.f, 0.f, 0.f, 0.f};
        return;
    }
    const long NX = 8388608, NW = 1048576;
    long g = ((long)blockIdx.x * blockDim.x + threadIdx.x) * 4;
    const float* src;
    long off;
    if (g < NX)             { src = x;  off = g; }
    else if (g < NX + NW)   { src = wq; off = g - NX; }
    else if (g < NX + 2*NW) { src = wk; off = g - NX - NW; }
    else                    { src = wv; off = g - NX - 2*NW; }
    float4 v = *(const float4*)(src + off);
    ushort4 o;
    o.x = f2bf(v.x); o.y = f2bf(v.y); o.z = f2bf(v.z); o.w = f2bf(v.w);
    *(ushort4*)(dst + g) = o;
}

// ---------------------------------------------------------------------------
// Fused projections: z=0 -> Q = x Wq^T, z=1 -> K = x Wk^T, z=2 -> V^T = Wv x^T
// ---------------------------------------------------------------------------
__global__ __launch_bounds__(512, 6) void qkv_kernel(
    const ushort_t* __restrict__ xb,
    const ushort_t* __restrict__ wqb,
    const ushort_t* __restrict__ wkb,
    const ushort_t* __restrict__ wvb,
    ushort_t* __restrict__ Qb,
    ushort_t* __restrict__ Kb,
    ushort_t* __restrict__ VTb) {

    __shared__ __align__(16) ushort_t As[128 * 32];
    __shared__ __align__(16) ushort_t Bs[128 * 32];

    const int z = blockIdx.z;
    const ushort_t *A, *B;
    ushort_t* C;
    int ldc, tile_m, tile_n;
    if (z == 2) {  // V^T = Wv x^T : M=1024 (x), N=8192 (y)
        A = wvb; B = xb; C = VTb; ldc = 8192;
        tile_m = blockIdx.x * 128; tile_n = blockIdx.y * 128;
    } else {       // Q/K = x W^T : M=8192 (y), N=1024 (x)
        A = xb; B = z ? wkb : wqb; C = z ? Kb : Qb; ldc = 1024;
        tile_m = blockIdx.y * 128; tile_n = blockIdx.x * 128;
    }

    floatx4 acc[4][2];
    gemm_core512(A, 1024, B, 1024, 1024, tile_m, tile_n, As, Bs, acc);

    const int lane = threadIdx.x & 63, wave = threadIdx.x >> 6;
    const int wm = wave >> 2, wn = wave & 3, quad = lane >> 4, l16 = lane & 15;
#pragma unroll
    for (int im = 0; im < 4; im++)
#pragma unroll
        for (int r = 0; r < 4; r++) {
            int row = tile_m + wm * 64 + im * 16 + quad * 4 + r;
#pragma unroll
            for (int in = 0; in < 2; in++) {
                int col = tile_n + wn * 32 + in * 16 + l16;
                C[(long)row * ldc + col] = f2bf(acc[im][in][r]);
            }
        }
}

// ---------------------------------------------------------------------------
// P = exp(scale * Q K^T) per batch + fused row-sum atomics into lsum
// ---------------------------------------------------------------------------
__global__ __launch_bounds__(512, 6) void pexp_kernel(
    const ushort_t* __restrict__ Qb,
    const ushort_t* __restrict__ Kb,
    ushort_t* __restrict__ Pb,
    float* __restrict__ lsum) {

    __shared__ __align__(16) ushort_t As[128 * 32];
    __shared__ __align__(16) ushort_t Bs[128 * 32];

    const int z = blockIdx.z;
    const ushort_t* A = Qb + (long)z * 2097152;
    const ushort_t* B = Kb + (long)z * 2097152;
    ushort_t* C = Pb + (long)z * 4194304;
    float* l = lsum + z * 2048;
    const int tile_m = blockIdx.y * 128;
    const int tile_n = blockIdx.x * 128;

    floatx4 acc[4][2];
    gemm_core512(A, 1024, B, 1024, 1024, tile_m, tile_n, As, Bs, acc);

    const float scale = 0.022097086912079608f;  // 1/sqrt(2048)
    const int lane = threadIdx.x & 63, wave = threadIdx.x >> 6;
    const int wm = wave >> 2, wn = wave & 3, quad = lane >> 4, l16 = lane & 15;
#pragma unroll
    for (int im = 0; im < 4; im++)
#pragma unroll
        for (int r = 0; r < 4; r++) {
            int row = tile_m + wm * 64 + im * 16 + quad * 4 + r;
            float psum = 0.f;
#pragma unroll
            for (int in = 0; in < 2; in++) {
                int col = tile_n + wn * 32 + in * 16 + l16;
                float e = __expf(acc[im][in][r] * scale);
                C[(long)row * 2048 + col] = f2bf(e);
                psum += e;
            }
            psum += __shfl_xor(psum, 1, 64);
            psum += __shfl_xor(psum, 2, 64);
            psum += __shfl_xor(psum, 4, 64);
            psum += __shfl_xor(psum, 8, 64);
            if (l16 == 0) atomicAdd(&l[row], psum);
        }
}

// ---------------------------------------------------------------------------
// out = (P V) / l per batch
// ---------------------------------------------------------------------------
__global__ __launch_bounds__(512, 6) void out_kernel(
    const ushort_t* __restrict__ Pb,
    const ushort_t* __restrict__ VTb,
    float* __restrict__ out,
    const float* __restrict__ lsum) {

    __shared__ __align__(16) ushort_t As[128 * 32];
    __shared__ __align__(16) ushort_t Bs[128 * 32];

    const int z = blockIdx.z;
    const ushort_t* A = Pb + (long)z * 4194304;   // [2048][2048]
    const ushort_t* B = VTb + (long)z * 2048;     // ldb=8192, batch col slice
    float* C = out + (long)z * 2097152;
    const float* l = lsum + z * 2048;
    const int tile_m = blockIdx.y * 128;
    const int tile_n = blockIdx.x * 128;

    floatx4 acc[4][2];
    gemm_core512(A, 2048, B, 8192, 2048, tile_m, tile_n, As, Bs, acc);

    const int lane = threadIdx.x & 63, wave = threadIdx.x >> 6;
    const int wm = wave >> 2, wn = wave & 3, quad = lane >> 4, l16 = lane & 15;
#pragma unroll
    for (int im = 0; im < 4; im++)
#pragma unroll
        for (int r = 0; r < 4; r++) {
            int row = tile_m + wm * 64 + im * 16 + quad * 4 + r;
            float li = 1.0f / l[row];
#pragma unroll
            for (int in = 0; in < 2; in++) {
                int col = tile_n + wn * 32 + in * 16 + l16;
                C[(long)row * 1024 + col] = acc[im][in][r] * li;
            }
        }
}

// ---------------------------------------------------------------------------
extern "C" void kernel_launch(void* const* d_in, const int* in_sizes, int n_in,
                              void* d_out, int out_size, void* d_ws, size_t ws_size,
                              hipStream_t stream) {
    const float* x  = (const float*)d_in[0];
    const float* wq = (const float*)d_in[1];
    const float* wk = (const float*)d_in[2];
    const float* wv = (const float*)d_in[3];

    ushort_t* xb  = (ushort_t*)d_ws;          // [8192,1024] bf16
    ushort_t* wqb = xb  + 8388608;            // [1024,1024]
    ushort_t* wkb = wqb + 1048576;
    ushort_t* wvb = wkb + 1048576;
    ushort_t* Qb  = wvb + 1048576;            // [8192,1024]
    ushort_t* Kb  = Qb  + 8388608;            // [8192,1024]
    ushort_t* VTb = Kb  + 8388608;            // [1024,8192]
    ushort_t* Pb  = VTb + 8388608;            // [4][2048][2048]
    float*    lsum = (float*)(Pb + 16777216); // [4][2048] fp32 row sums
    float*    out  = (float*)d_out;

    // 1) fp32->bf16 (+ zero lsum in trailing 8 blocks)
    cvt_kernel<<<11272, 256, 0, stream>>>(x, wq, wk, wv, xb, lsum);

    // 2) Q, K, V^T in one dispatch (1536 blocks x 512 thr)
    qkv_kernel<<<dim3(8, 64, 3), 512, 0, stream>>>(xb, wqb, wkb, wvb, Qb, Kb, VTb);

    // 3) P = exp(scale * Q K^T) + row sums (1024 blocks)
    pexp_kernel<<<dim3(16, 16, 4), 512, 0, stream>>>(Qb, Kb, Pb, lsum);

    // 4) out = (P V) / l (512 blocks)
    out_kernel<<<dim3(8, 16, 4), 512, 0, stream>>>(Pb, VTb, out, lsum);
}